// Round 11
// baseline (861.338 us; speedup 1.0000x reference)
//
#include <hip/hip_runtime.h>
#include <cmath>

typedef __attribute__((ext_vector_type(8))) short bf16x8;
typedef __attribute__((ext_vector_type(4))) float f32x4;

__device__ inline unsigned short f2bf_rne(float f) {
    unsigned int u = __float_as_uint(f);
    unsigned int r = (u + 0x7FFFu + ((u >> 16) & 1u)) >> 16;
    return (unsigned short)r;
}
__device__ inline float bf2f(unsigned short h) {
    return __uint_as_float(((unsigned int)h) << 16);
}

// ---------------- CSR build via two-level counting sort (R7/R8) ----------------
// Packing (dlocal<<17|src) requires N <= 2^17.

constexpr int CB = 256;

__global__ __launch_bounds__(256) void k_bucket_hist(const int* __restrict__ src,
                                                     const int* __restrict__ dst,
                                                     int* __restrict__ gH,
                                                     int E, int K, int scanN, int chunk) {
    extern __shared__ int lds[];
    int* hd = lds; int* hs = lds + K;
    for (int i = threadIdx.x; i < 2 * K; i += 256) lds[i] = 0;
    __syncthreads();
    int lo = blockIdx.x * chunk;
    int hi = lo + chunk; if (hi > E) hi = E;
    for (int i = lo + threadIdx.x; i < hi; i += 256) {
        atomicAdd(&hd[dst[i] >> 6], 1);
        atomicAdd(&hs[src[i] >> 6], 1);
    }
    __syncthreads();
    for (int k = threadIdx.x; k < K; k += 256) {
        gH[(size_t)k * CB + blockIdx.x] = hd[k];
        gH[(size_t)(scanN + k * CB) + blockIdx.x] = hs[k];
    }
}

__global__ __launch_bounds__(256) void k_bucket_scatter(const int* __restrict__ src,
                                                        const int* __restrict__ dst,
                                                        const int* __restrict__ gHS,
                                                        int* __restrict__ sortedAll,
                                                        int E, int K, int scanN, int chunk) {
    extern __shared__ int lds[];
    int* bd = lds; int* bs = lds + K;
    for (int k = threadIdx.x; k < K; k += 256) {
        bd[k] = gHS[(size_t)k * CB + blockIdx.x];
        bs[k] = gHS[(size_t)(scanN + k * CB) + blockIdx.x];
    }
    __syncthreads();
    int lo = blockIdx.x * chunk;
    int hi = lo + chunk; if (hi > E) hi = E;
    for (int i = lo + threadIdx.x; i < hi; i += 256) {
        int d = dst[i], s = src[i];
        int pd = atomicAdd(&bd[d >> 6], 1);
        sortedAll[pd] = ((d & 63) << 17) | s;
        int ps = atomicAdd(&bs[s >> 6], 1);
        sortedAll[ps] = s;
    }
}

__global__ __launch_bounds__(256) void k_fine(const int* __restrict__ sortedAll,
                                              const int* __restrict__ gHS,
                                              int* __restrict__ rowptr,
                                              int* __restrict__ colidx,
                                              float* __restrict__ nsrc,
                                              float* __restrict__ ndst,
                                              int E, int K, int scanN, int N) {
    __shared__ int cnt[64], excl[64], rank[64];
    int kb = blockIdx.x;
    bool isDst = kb < K;
    int k = isDst ? kb : kb - K;
    int bstart, bend;
    if (isDst) {
        bstart = gHS[(size_t)k * CB];
        bend = (k + 1 < K) ? gHS[(size_t)(k + 1) * CB] : E;
    } else {
        bstart = gHS[(size_t)(scanN + k * CB)];
        bend = (k + 1 < K) ? gHS[(size_t)(scanN + (k + 1) * CB)] : 2 * E;
    }
    if (threadIdx.x < 64) { cnt[threadIdx.x] = 0; rank[threadIdx.x] = 0; }
    __syncthreads();
    if (isDst) {
        for (int i = bstart + threadIdx.x; i < bend; i += 256)
            atomicAdd(&cnt[sortedAll[i] >> 17], 1);
    } else {
        for (int i = bstart + threadIdx.x; i < bend; i += 256)
            atomicAdd(&cnt[sortedAll[i] & 63], 1);
    }
    __syncthreads();
    if (isDst) {
        if (threadIdx.x == 0) {
            int r = 0;
            for (int j = 0; j < 64; j++) { excl[j] = r; r += cnt[j]; }
        }
        __syncthreads();
        int node0 = k << 6;
        if (threadIdx.x < 64) {
            int node = node0 + threadIdx.x;
            if (node < N) {
                rowptr[node] = bstart + excl[threadIdx.x];
                int c = cnt[threadIdx.x];
                ndst[node] = c > 0 ? rsqrtf((float)c) : 0.f;
            }
        }
        if (k == 0 && threadIdx.x == 0) rowptr[N] = E;
        for (int i = bstart + threadIdx.x; i < bend; i += 256) {
            int v = sortedAll[i];
            int n = v >> 17;
            int r = atomicAdd(&rank[n], 1);
            colidx[bstart + excl[n] + r] = v & 0x1FFFF;
        }
    } else {
        int node = (k << 6) + threadIdx.x;
        if (threadIdx.x < 64 && node < N) {
            int c = cnt[threadIdx.x];
            nsrc[node] = c > 0 ? rsqrtf((float)c) : 0.f;
        }
    }
}

// W (fp32, k-major [k][n]) -> Wt hi/lo (bf16, n-major [n][k]), all 4 layers
__global__ void k_prepW_all(const float* __restrict__ W0, const float* __restrict__ W1,
                            const float* __restrict__ W2, const float* __restrict__ W3,
                            unsigned short* __restrict__ h0, unsigned short* __restrict__ l0,
                            unsigned short* __restrict__ h1, unsigned short* __restrict__ l1,
                            unsigned short* __restrict__ h2, unsigned short* __restrict__ l2,
                            unsigned short* __restrict__ h3, unsigned short* __restrict__ l3) {
    int i = blockIdx.x * 256 + threadIdx.x;
    const float* W; unsigned short* wh; unsigned short* wl; int N; int base;
    if      (i < 16384) { W = W0; wh = h0; wl = l0; N = 128; base = i; }
    else if (i < 32768) { W = W1; wh = h1; wl = l1; N = 128; base = i - 16384; }
    else if (i < 49152) { W = W2; wh = h2; wl = l2; N = 128; base = i - 32768; }
    else if (i < 57344) { W = W3; wh = h3; wl = l3; N = 64;  base = i - 49152; }
    else return;
    int n = base >> 7, k = base & 127;
    float w = W[k * N + n];
    unsigned short hb = f2bf_rne(w);
    unsigned short lb = f2bf_rne(w - bf2f(hb));
    wh[base] = hb; wl[base] = lb;
}

// ---------------- device-wide exclusive scan (tile = 2048) ----------------

constexpr int SCAN_TILE = 2048;

__global__ __launch_bounds__(256) void k_scan_partial(const int* __restrict__ deg,
                                                      int* __restrict__ tilesum, int n) {
    __shared__ int red[256];
    int base = blockIdx.x * SCAN_TILE;
    int s = 0;
    for (int i = threadIdx.x; i < SCAN_TILE; i += 256) {
        int idx = base + i;
        if (idx < n) s += deg[idx];
    }
    red[threadIdx.x] = s;
    __syncthreads();
    for (int off = 128; off > 0; off >>= 1) {
        if (threadIdx.x < off) red[threadIdx.x] += red[threadIdx.x + off];
        __syncthreads();
    }
    if (threadIdx.x == 0) tilesum[blockIdx.x] = red[0];
}

__global__ void k_scan_tiles(int* __restrict__ tilesum, int* __restrict__ outArr,
                             int numTiles, int n) {
    if (threadIdx.x == 0 && blockIdx.x == 0) {
        int acc = 0;
        for (int i = 0; i < numTiles; i++) { int v = tilesum[i]; tilesum[i] = acc; acc += v; }
        outArr[n] = acc;
    }
}

__global__ __launch_bounds__(256) void k_scan_final(const int* __restrict__ deg,
                                                    const int* __restrict__ tilesum,
                                                    int* __restrict__ outArr, int n) {
    __shared__ int red[256];
    int base = blockIdx.x * SCAN_TILE;
    int lo = base + threadIdx.x * 8;
    int v[8]; int s = 0;
#pragma unroll
    for (int j = 0; j < 8; j++) {
        int idx = lo + j;
        v[j] = (idx < n) ? deg[idx] : 0;
        s += v[j];
    }
    red[threadIdx.x] = s;
    __syncthreads();
    for (int off = 1; off < 256; off <<= 1) {
        int x = red[threadIdx.x];
        int add = (threadIdx.x >= off) ? red[threadIdx.x - off] : 0;
        __syncthreads();
        red[threadIdx.x] = x + add;
        __syncthreads();
    }
    int excl = tilesum[blockIdx.x] + (threadIdx.x ? red[threadIdx.x - 1] : 0);
#pragma unroll
    for (int j = 0; j < 8; j++) {
        int idx = lo + j;
        if (idx < n) outArr[idx] = excl;
        excl += v[j];
    }
}

// ---------------- GEMM: LDS-free direct-fragment MFMA (R10) ----------------
// MFMA fragments load straight from global: A-frag = 16B contiguous at
// xhi[row*128+ko] (16 rows x 64B per wave instr = cache-line-perfect, each row
// read once per wave); B-frag from n-major wt (64KB, L2-hot, shared by all
// blocks). No LDS, no barriers, no staging: wave = 16 rows x all DOUT cols,
// 4 kq steps x (2 A-loads + 2*NT B-loads + 3*NT MFMA). Same fragment mapping
// and k-ascending accumulate order as R6 -> bit-identical output.

template <int DOUT, int SRC>
__global__ __launch_bounds__(256) void k_gemm_direct(
        const float* __restrict__ xf,
        const unsigned short* __restrict__ xhi, const unsigned short* __restrict__ xlo,
        const unsigned short* __restrict__ wth, const unsigned short* __restrict__ wtl,
        const float* __restrict__ nsrc, float* __restrict__ h, int nrows) {
    constexpr int NT = DOUT / 16;          // n-tiles per wave (8 or 4)
    int wv = (blockIdx.x * 256 + threadIdx.x) >> 6;
    int lane = threadIdx.x & 63;
    int quad = lane >> 4, l16 = lane & 15;
    int r0 = wv * 16;
    if (r0 >= nrows) return;

    int rowA = r0 + l16; if (rowA >= nrows) rowA = nrows - 1;   // clamped load row

    f32x4 acc[NT];
#pragma unroll
    for (int nt = 0; nt < NT; nt++) acc[nt] = (f32x4){0.f, 0.f, 0.f, 0.f};

#pragma unroll
    for (int kq = 0; kq < 4; kq++) {
        int ko = kq * 32 + quad * 8;
        bf16x8 ah, al;
        if (SRC == 0) {
            const float* xp = &xf[(size_t)rowA * 128 + ko];
            float4 x0 = *(const float4*)xp;
            float4 x1 = *(const float4*)(xp + 4);
            union { bf16x8 v; unsigned short u[8]; } H, L;
            float xs[8] = {x0.x, x0.y, x0.z, x0.w, x1.x, x1.y, x1.z, x1.w};
#pragma unroll
            for (int j = 0; j < 8; j++) {
                H.u[j] = f2bf_rne(xs[j]);
                L.u[j] = f2bf_rne(xs[j] - bf2f(H.u[j]));
            }
            ah = H.v; al = L.v;
        } else {
            ah = *(const bf16x8*)&xhi[(size_t)rowA * 128 + ko];
            al = *(const bf16x8*)&xlo[(size_t)rowA * 128 + ko];
        }
#pragma unroll
        for (int nt = 0; nt < NT; nt++) {
            int n = nt * 16 + l16;
            bf16x8 bh = *(const bf16x8*)&wth[n * 128 + ko];
            bf16x8 bl = *(const bf16x8*)&wtl[n * 128 + ko];
            acc[nt] = __builtin_amdgcn_mfma_f32_16x16x32_bf16(ah, bh, acc[nt], 0, 0, 0);
            acc[nt] = __builtin_amdgcn_mfma_f32_16x16x32_bf16(ah, bl, acc[nt], 0, 0, 0);
            acc[nt] = __builtin_amdgcn_mfma_f32_16x16x32_bf16(al, bh, acc[nt], 0, 0, 0);
        }
    }

#pragma unroll
    for (int r = 0; r < 4; r++) {
        int row = r0 + quad * 4 + r;
        if (row < nrows) {
            float nm = nsrc[row];
#pragma unroll
            for (int nt = 0; nt < NT; nt++)
                h[(size_t)row * DOUT + nt * 16 + l16] = acc[nt][r] * nm;
        }
    }
}

// ---------------- aggregation: wave-per-node, MLP=8 (R9 form, unchanged) ----------------

template <int D, int MODE>
__global__ __launch_bounds__(256) void k_aggregate(const float* __restrict__ h,
                                                   const int* __restrict__ rowptr,
                                                   const int* __restrict__ colidx,
                                                   const float* __restrict__ ndst,
                                                   const float* __restrict__ bias,
                                                   float* __restrict__ out,
                                                   unsigned short* __restrict__ ohi,
                                                   unsigned short* __restrict__ olo,
                                                   int n) {
    constexpr int FB = D / 4;
    constexpr int G  = 64 / FB;
    constexpr int U  = 8;
    constexpr int UG = U * G;
    int wid  = (blockIdx.x * 256 + threadIdx.x) >> 6;
    int lane = threadIdx.x & 63;
    int fb = lane & (FB - 1);
    int g  = lane / FB;
    int waveCount = gridDim.x * 4;
    const float4* h4 = (const float4*)h;

    for (int node = wid; node < n; node += waveCount) {
        int beg = rowptr[node], end = rowptr[node + 1];
        float4 a0 = {0, 0, 0, 0}, a1 = {0, 0, 0, 0}, a2 = {0, 0, 0, 0}, a3 = {0, 0, 0, 0};

        for (int base = beg; base < end; base += 64) {
            int m = end - base; if (m > 64) m = 64;
            int cv = colidx[base + (lane < m ? lane : 0)];
            int nb = (m + UG - 1) / UG;       // wave-uniform trip count
            for (int b = 0; b < nb; b++) {
                int s[U]; float w[U];
#pragma unroll
                for (int u = 0; u < U; u++) {
                    int j = b * UG + u * G + g;
                    int q = j < m ? j : 0;
                    w[u] = j < m ? 1.f : 0.f;
                    s[u] = __shfl(cv, q);
                }
                float4 v[U];
#pragma unroll
                for (int u = 0; u < U; u++)
                    v[u] = h4[(size_t)s[u] * FB + fb];
#pragma unroll
                for (int u = 0; u < U; u += 4) {
                    a0.x = fmaf(v[u].x, w[u], a0.x); a0.y = fmaf(v[u].y, w[u], a0.y);
                    a0.z = fmaf(v[u].z, w[u], a0.z); a0.w = fmaf(v[u].w, w[u], a0.w);
                    a1.x = fmaf(v[u+1].x, w[u+1], a1.x); a1.y = fmaf(v[u+1].y, w[u+1], a1.y);
                    a1.z = fmaf(v[u+1].z, w[u+1], a1.z); a1.w = fmaf(v[u+1].w, w[u+1], a1.w);
                    a2.x = fmaf(v[u+2].x, w[u+2], a2.x); a2.y = fmaf(v[u+2].y, w[u+2], a2.y);
                    a2.z = fmaf(v[u+2].z, w[u+2], a2.z); a2.w = fmaf(v[u+2].w, w[u+2], a2.w);
                    a3.x = fmaf(v[u+3].x, w[u+3], a3.x); a3.y = fmaf(v[u+3].y, w[u+3], a3.y);
                    a3.z = fmaf(v[u+3].z, w[u+3], a3.z); a3.w = fmaf(v[u+3].w, w[u+3], a3.w);
                }
            }
        }

        float4 acc;
        acc.x = (a0.x + a1.x) + (a2.x + a3.x);
        acc.y = (a0.y + a1.y) + (a2.y + a3.y);
        acc.z = (a0.z + a1.z) + (a2.z + a3.z);
        acc.w = (a0.w + a1.w) + (a2.w + a3.w);
#pragma unroll
        for (int off = FB; off < 64; off <<= 1) {
            acc.x += __shfl_xor(acc.x, off);
            acc.y += __shfl_xor(acc.y, off);
            acc.z += __shfl_xor(acc.z, off);
            acc.w += __shfl_xor(acc.w, off);
        }
        if (g == 0) {
            float nd = ndst[node];
            float4 bv = ((const float4*)bias)[fb];
            float4 v;
            v.x = acc.x * nd + bv.x;
            v.y = acc.y * nd + bv.y;
            v.z = acc.z * nd + bv.z;
            v.w = acc.w * nd + bv.w;
            if (MODE == 1) {
                v.x = tanhf(v.x); v.y = tanhf(v.y);
                v.z = tanhf(v.z); v.w = tanhf(v.w);
                ushort4 hv, lv;
                hv.x = f2bf_rne(v.x); lv.x = f2bf_rne(v.x - bf2f(hv.x));
                hv.y = f2bf_rne(v.y); lv.y = f2bf_rne(v.y - bf2f(hv.y));
                hv.z = f2bf_rne(v.z); lv.z = f2bf_rne(v.z - bf2f(hv.z));
                hv.w = f2bf_rne(v.w); lv.w = f2bf_rne(v.w - bf2f(hv.w));
                *(ushort4*)&ohi[(size_t)node * D + fb * 4] = hv;
                *(ushort4*)&olo[(size_t)node * D + fb * 4] = lv;
            } else {
                ((float4*)out)[(size_t)node * FB + fb] = v;
            }
        }
    }
}

// ---------------- host ----------------

extern "C" void kernel_launch(void* const* d_in, const int* in_sizes, int n_in,
                              void* d_out, int out_size, void* d_ws, size_t ws_size,
                              hipStream_t stream) {
    const float* features = (const float*)d_in[0];
    const int* edges      = (const int*)d_in[1];
    const float* W0 = (const float*)d_in[2]; const float* b0 = (const float*)d_in[3];
    const float* W1 = (const float*)d_in[4]; const float* b1 = (const float*)d_in[5];
    const float* W2 = (const float*)d_in[6]; const float* b2 = (const float*)d_in[7];
    const float* W3 = (const float*)d_in[8]; const float* b3 = (const float*)d_in[9];
    float* out = (float*)d_out;

    const int N = in_sizes[0] / 128;
    const int E = in_sizes[1] / 2;
    const int* src = edges;
    const int* dst = edges + E;
    const int K = (N + 63) >> 6;
    const int chunk = (E + CB - 1) / CB;
    const int scanN = K * CB;
    const int n2 = 2 * scanN;
    const int numTiles = (n2 + SCAN_TILE - 1) / SCAN_TILE;
    const size_t dynLds = (size_t)2 * K * sizeof(int);

    char* p = (char*)d_ws;
    float* bufH            = (float*)p;          p += (size_t)N * 128 * 4;
    unsigned short* xhi    = (unsigned short*)p; p += (size_t)N * 128 * 2;
    unsigned short* xlo    = (unsigned short*)p; p += (size_t)N * 128 * 2;
    int*   rowptr = (int*)p;   p += (((size_t)(N + 1) * 4 + 15) / 16) * 16;
    int*   colidx = (int*)p;   p += (size_t)E * 4;
    float* nsrc   = (float*)p; p += (size_t)N * 4;
    float* ndst   = (float*)p; p += (size_t)N * 4;
    int*   tilesum= (int*)p;   p += (((size_t)(numTiles + 1) * 4 + 15) / 16) * 16;
    unsigned short* wt0h = (unsigned short*)p; p += 16384 * 2;
    unsigned short* wt0l = (unsigned short*)p; p += 16384 * 2;
    unsigned short* wt1h = (unsigned short*)p; p += 16384 * 2;
    unsigned short* wt1l = (unsigned short*)p; p += 16384 * 2;
    unsigned short* wt2h = (unsigned short*)p; p += 16384 * 2;
    unsigned short* wt2l = (unsigned short*)p; p += 16384 * 2;
    unsigned short* wt3h = (unsigned short*)p; p += 8192 * 2;
    unsigned short* wt3l = (unsigned short*)p; p += 8192 * 2;

    // transient counting-sort buffers aliased into xhi/xlo region
    char* q = (char*)xhi;
    int* sortedAll = (int*)q; q += (size_t)2 * E * 4;
    int* gH        = (int*)q; q += (size_t)n2 * 4;
    int* gHS       = (int*)q; q += (size_t)(n2 + 1) * 4;

    k_prepW_all<<<224, 256, 0, stream>>>(W0, W1, W2, W3, wt0h, wt0l, wt1h, wt1l,
                                         wt2h, wt2l, wt3h, wt3l);
    k_bucket_hist<<<CB, 256, dynLds, stream>>>(src, dst, gH, E, K, scanN, chunk);
    k_scan_partial<<<numTiles, 256, 0, stream>>>(gH, tilesum, n2);
    k_scan_tiles<<<1, 64, 0, stream>>>(tilesum, gHS, numTiles, n2);
    k_scan_final<<<numTiles, 256, 0, stream>>>(gH, tilesum, gHS, n2);
    k_bucket_scatter<<<CB, 256, dynLds, stream>>>(src, dst, gHS, sortedAll, E, K, scanN, chunk);
    k_fine<<<2 * K, 256, 0, stream>>>(sortedAll, gHS, rowptr, colidx, nsrc, ndst, E, K, scanN, N);

    int gblk = (N + 63) / 64;   // 4 waves/block x 16 rows/wave = 64 rows/block
    int ablk = 8192;
    k_gemm_direct<128, 0><<<gblk, 256, 0, stream>>>(features, nullptr, nullptr, wt0h, wt0l, nsrc, bufH, N);
    k_aggregate<128, 1><<<ablk, 256, 0, stream>>>(bufH, rowptr, colidx, ndst, b0, nullptr, xhi, xlo, N);
    k_gemm_direct<128, 1><<<gblk, 256, 0, stream>>>(nullptr, xhi, xlo, wt1h, wt1l, nsrc, bufH, N);
    k_aggregate<128, 1><<<ablk, 256, 0, stream>>>(bufH, rowptr, colidx, ndst, b1, nullptr, xhi, xlo, N);
    k_gemm_direct<128, 1><<<gblk, 256, 0, stream>>>(nullptr, xhi, xlo, wt2h, wt2l, nsrc, bufH, N);
    k_aggregate<128, 1><<<ablk, 256, 0, stream>>>(bufH, rowptr, colidx, ndst, b2, nullptr, xhi, xlo, N);
    k_gemm_direct<64, 1><<<gblk, 256, 0, stream>>>(nullptr, xhi, xlo, wt3h, wt3l, nsrc, bufH, N);
    k_aggregate<64, 0><<<ablk, 256, 0, stream>>>(bufH, rowptr, colidx, ndst, b3, out, nullptr, nullptr, N);
}

// Round 12
// 730.388 us; speedup vs baseline: 1.1793x; 1.1793x over previous
//
#include <hip/hip_runtime.h>
#include <cmath>

typedef __attribute__((ext_vector_type(8))) short bf16x8;
typedef __attribute__((ext_vector_type(4))) float f32x4;

__device__ inline unsigned short f2bf_rne(float f) {
    unsigned int u = __float_as_uint(f);
    unsigned int r = (u + 0x7FFFu + ((u >> 16) & 1u)) >> 16;
    return (unsigned short)r;
}
__device__ inline float bf2f(unsigned short h) {
    return __uint_as_float(((unsigned int)h) << 16);
}

// ---------------- CSR build via two-level counting sort (R7/R8) ----------------
// Packing (dlocal<<17|src) requires N <= 2^17.

constexpr int CB = 256;

__global__ __launch_bounds__(256) void k_bucket_hist(const int* __restrict__ src,
                                                     const int* __restrict__ dst,
                                                     int* __restrict__ gH,
                                                     int E, int K, int scanN, int chunk) {
    extern __shared__ int lds[];
    int* hd = lds; int* hs = lds + K;
    for (int i = threadIdx.x; i < 2 * K; i += 256) lds[i] = 0;
    __syncthreads();
    int lo = blockIdx.x * chunk;
    int hi = lo + chunk; if (hi > E) hi = E;
    for (int i = lo + threadIdx.x; i < hi; i += 256) {
        atomicAdd(&hd[dst[i] >> 6], 1);
        atomicAdd(&hs[src[i] >> 6], 1);
    }
    __syncthreads();
    for (int k = threadIdx.x; k < K; k += 256) {
        gH[(size_t)k * CB + blockIdx.x] = hd[k];
        gH[(size_t)(scanN + k * CB) + blockIdx.x] = hs[k];
    }
}

__global__ __launch_bounds__(256) void k_bucket_scatter(const int* __restrict__ src,
                                                        const int* __restrict__ dst,
                                                        const int* __restrict__ gHS,
                                                        int* __restrict__ sortedAll,
                                                        int E, int K, int scanN, int chunk) {
    extern __shared__ int lds[];
    int* bd = lds; int* bs = lds + K;
    for (int k = threadIdx.x; k < K; k += 256) {
        bd[k] = gHS[(size_t)k * CB + blockIdx.x];
        bs[k] = gHS[(size_t)(scanN + k * CB) + blockIdx.x];
    }
    __syncthreads();
    int lo = blockIdx.x * chunk;
    int hi = lo + chunk; if (hi > E) hi = E;
    for (int i = lo + threadIdx.x; i < hi; i += 256) {
        int d = dst[i], s = src[i];
        int pd = atomicAdd(&bd[d >> 6], 1);
        sortedAll[pd] = ((d & 63) << 17) | s;
        int ps = atomicAdd(&bs[s >> 6], 1);
        sortedAll[ps] = s;
    }
}

__global__ __launch_bounds__(256) void k_fine(const int* __restrict__ sortedAll,
                                              const int* __restrict__ gHS,
                                              int* __restrict__ rowptr,
                                              int* __restrict__ colidx,
                                              float* __restrict__ nsrc,
                                              float* __restrict__ ndst,
                                              int E, int K, int scanN, int N) {
    __shared__ int cnt[64], excl[64], rank[64];
    int kb = blockIdx.x;
    bool isDst = kb < K;
    int k = isDst ? kb : kb - K;
    int bstart, bend;
    if (isDst) {
        bstart = gHS[(size_t)k * CB];
        bend = (k + 1 < K) ? gHS[(size_t)(k + 1) * CB] : E;
    } else {
        bstart = gHS[(size_t)(scanN + k * CB)];
        bend = (k + 1 < K) ? gHS[(size_t)(scanN + (k + 1) * CB)] : 2 * E;
    }
    if (threadIdx.x < 64) { cnt[threadIdx.x] = 0; rank[threadIdx.x] = 0; }
    __syncthreads();
    if (isDst) {
        for (int i = bstart + threadIdx.x; i < bend; i += 256)
            atomicAdd(&cnt[sortedAll[i] >> 17], 1);
    } else {
        for (int i = bstart + threadIdx.x; i < bend; i += 256)
            atomicAdd(&cnt[sortedAll[i] & 63], 1);
    }
    __syncthreads();
    if (isDst) {
        if (threadIdx.x == 0) {
            int r = 0;
            for (int j = 0; j < 64; j++) { excl[j] = r; r += cnt[j]; }
        }
        __syncthreads();
        int node0 = k << 6;
        if (threadIdx.x < 64) {
            int node = node0 + threadIdx.x;
            if (node < N) {
                rowptr[node] = bstart + excl[threadIdx.x];
                int c = cnt[threadIdx.x];
                ndst[node] = c > 0 ? rsqrtf((float)c) : 0.f;
            }
        }
        if (k == 0 && threadIdx.x == 0) rowptr[N] = E;
        for (int i = bstart + threadIdx.x; i < bend; i += 256) {
            int v = sortedAll[i];
            int n = v >> 17;
            int r = atomicAdd(&rank[n], 1);
            colidx[bstart + excl[n] + r] = v & 0x1FFFF;
        }
    } else {
        int node = (k << 6) + threadIdx.x;
        if (threadIdx.x < 64 && node < N) {
            int c = cnt[threadIdx.x];
            nsrc[node] = c > 0 ? rsqrtf((float)c) : 0.f;
        }
    }
}

// W (fp32, k-major [k][n]) -> Wt hi/lo (bf16, n-major [n][k]), all 4 layers
__global__ void k_prepW_all(const float* __restrict__ W0, const float* __restrict__ W1,
                            const float* __restrict__ W2, const float* __restrict__ W3,
                            unsigned short* __restrict__ h0, unsigned short* __restrict__ l0,
                            unsigned short* __restrict__ h1, unsigned short* __restrict__ l1,
                            unsigned short* __restrict__ h2, unsigned short* __restrict__ l2,
                            unsigned short* __restrict__ h3, unsigned short* __restrict__ l3) {
    int i = blockIdx.x * 256 + threadIdx.x;
    const float* W; unsigned short* wh; unsigned short* wl; int N; int base;
    if      (i < 16384) { W = W0; wh = h0; wl = l0; N = 128; base = i; }
    else if (i < 32768) { W = W1; wh = h1; wl = l1; N = 128; base = i - 16384; }
    else if (i < 49152) { W = W2; wh = h2; wl = l2; N = 128; base = i - 32768; }
    else if (i < 57344) { W = W3; wh = h3; wl = l3; N = 64;  base = i - 49152; }
    else return;
    int n = base >> 7, k = base & 127;
    float w = W[k * N + n];
    unsigned short hb = f2bf_rne(w);
    unsigned short lb = f2bf_rne(w - bf2f(hb));
    wh[base] = hb; wl[base] = lb;
}

// ---------------- device-wide exclusive scan (tile = 2048) ----------------

constexpr int SCAN_TILE = 2048;

__global__ __launch_bounds__(256) void k_scan_partial(const int* __restrict__ deg,
                                                      int* __restrict__ tilesum, int n) {
    __shared__ int red[256];
    int base = blockIdx.x * SCAN_TILE;
    int s = 0;
    for (int i = threadIdx.x; i < SCAN_TILE; i += 256) {
        int idx = base + i;
        if (idx < n) s += deg[idx];
    }
    red[threadIdx.x] = s;
    __syncthreads();
    for (int off = 128; off > 0; off >>= 1) {
        if (threadIdx.x < off) red[threadIdx.x] += red[threadIdx.x + off];
        __syncthreads();
    }
    if (threadIdx.x == 0) tilesum[blockIdx.x] = red[0];
}

__global__ void k_scan_tiles(int* __restrict__ tilesum, int* __restrict__ outArr,
                             int numTiles, int n) {
    if (threadIdx.x == 0 && blockIdx.x == 0) {
        int acc = 0;
        for (int i = 0; i < numTiles; i++) { int v = tilesum[i]; tilesum[i] = acc; acc += v; }
        outArr[n] = acc;
    }
}

__global__ __launch_bounds__(256) void k_scan_final(const int* __restrict__ deg,
                                                    const int* __restrict__ tilesum,
                                                    int* __restrict__ outArr, int n) {
    __shared__ int red[256];
    int base = blockIdx.x * SCAN_TILE;
    int lo = base + threadIdx.x * 8;
    int v[8]; int s = 0;
#pragma unroll
    for (int j = 0; j < 8; j++) {
        int idx = lo + j;
        v[j] = (idx < n) ? deg[idx] : 0;
        s += v[j];
    }
    red[threadIdx.x] = s;
    __syncthreads();
    for (int off = 1; off < 256; off <<= 1) {
        int x = red[threadIdx.x];
        int add = (threadIdx.x >= off) ? red[threadIdx.x - off] : 0;
        __syncthreads();
        red[threadIdx.x] = x + add;
        __syncthreads();
    }
    int excl = tilesum[blockIdx.x] + (threadIdx.x ? red[threadIdx.x - 1] : 0);
#pragma unroll
    for (int j = 0; j < 8; j++) {
        int idx = lo + j;
        if (idx < n) outArr[idx] = excl;
        excl += v[j];
    }
}

// ---------------- GEMM: hybrid — B in LDS, A direct from global (R11) ----------------
// R10 post-mortem: B-from-global re-read 64KB/wave from L2 (+25us/GEMM); A-direct
// was the sound half (each row read once, 64B-granule perfect). So: B staged in
// LDS per kh-half (reused NT times per kq, ds_read latency), A straight from
// global. LDS 36.9KB (DOUT=128) -> 4 blocks/CU vs R6's 55.3KB/2 blocks.
// Same fragment mapping + ascending-k accumulate per element as R6/R10 ->
// bit-identical output (absmax tripwire: must stay 0.0001220703).

template <int DOUT, int SRC>
__global__ __launch_bounds__(256) void k_gemm_hyb(
        const float* __restrict__ xf,
        const unsigned short* __restrict__ xhi, const unsigned short* __restrict__ xlo,
        const unsigned short* __restrict__ wth, const unsigned short* __restrict__ wtl,
        const float* __restrict__ nsrc, float* __restrict__ h, int nrows) {
    constexpr int NT = DOUT / 16;    // n-tiles per wave (8 or 4), wave owns 16 rows x DOUT
    constexpr int LDK = 72;          // 64 k-half + 8 pad (16B-aligned rows)
    __shared__ unsigned short Bh[DOUT * LDK], Bl[DOUT * LDK];

    int tid = threadIdx.x;
    int lane = tid & 63;
    int wv = tid >> 6;
    int quad = lane >> 4, l16 = lane & 15;
    int r0 = blockIdx.x * 64 + wv * 16;
    int rowA = r0 + l16; if (rowA >= nrows) rowA = nrows - 1;   // clamped load row

    f32x4 acc[NT];
#pragma unroll
    for (int nt = 0; nt < NT; nt++) acc[nt] = (f32x4){0.f, 0.f, 0.f, 0.f};

    for (int kh = 0; kh < 2; kh++) {
        if (kh) __syncthreads();
        // stage B half: DOUT n-rows x 64 k
        for (int i = tid; i < DOUT * 16; i += 256) {
            int n = i >> 4, kb = i & 15;
            int koff = kh * 64 + kb * 4;
            *(ushort4*)&Bh[n * LDK + kb * 4] = *(const ushort4*)&wth[n * 128 + koff];
            *(ushort4*)&Bl[n * LDK + kb * 4] = *(const ushort4*)&wtl[n * 128 + koff];
        }
        __syncthreads();

#pragma unroll
        for (int kq = 0; kq < 2; kq++) {
            int koA = kh * 64 + kq * 32 + quad * 8;   // global k offset for A
            int koB = kq * 32 + quad * 8;             // LDS offset within half
            bf16x8 ah, al;
            if (SRC == 0) {
                const float* xp = &xf[(size_t)rowA * 128 + koA];
                float4 x0 = *(const float4*)xp;
                float4 x1 = *(const float4*)(xp + 4);
                union { bf16x8 v; unsigned short u[8]; } H, L;
                float xs[8] = {x0.x, x0.y, x0.z, x0.w, x1.x, x1.y, x1.z, x1.w};
#pragma unroll
                for (int j = 0; j < 8; j++) {
                    H.u[j] = f2bf_rne(xs[j]);
                    L.u[j] = f2bf_rne(xs[j] - bf2f(H.u[j]));
                }
                ah = H.v; al = L.v;
            } else {
                ah = *(const bf16x8*)&xhi[(size_t)rowA * 128 + koA];
                al = *(const bf16x8*)&xlo[(size_t)rowA * 128 + koA];
            }
#pragma unroll
            for (int nt = 0; nt < NT; nt++) {
                int n = nt * 16 + l16;
                bf16x8 bh = *(const bf16x8*)&Bh[n * LDK + koB];
                bf16x8 bl = *(const bf16x8*)&Bl[n * LDK + koB];
                acc[nt] = __builtin_amdgcn_mfma_f32_16x16x32_bf16(ah, bh, acc[nt], 0, 0, 0);
                acc[nt] = __builtin_amdgcn_mfma_f32_16x16x32_bf16(ah, bl, acc[nt], 0, 0, 0);
                acc[nt] = __builtin_amdgcn_mfma_f32_16x16x32_bf16(al, bh, acc[nt], 0, 0, 0);
            }
        }
    }

#pragma unroll
    for (int r = 0; r < 4; r++) {
        int row = r0 + quad * 4 + r;
        if (row < nrows) {
            float nm = nsrc[row];
#pragma unroll
            for (int nt = 0; nt < NT; nt++)
                h[(size_t)row * DOUT + nt * 16 + l16] = acc[nt][r] * nm;
        }
    }
}

// ---------------- aggregation: wave-per-node, MLP=8 (R9 form, unchanged) ----------------

template <int D, int MODE>
__global__ __launch_bounds__(256) void k_aggregate(const float* __restrict__ h,
                                                   const int* __restrict__ rowptr,
                                                   const int* __restrict__ colidx,
                                                   const float* __restrict__ ndst,
                                                   const float* __restrict__ bias,
                                                   float* __restrict__ out,
                                                   unsigned short* __restrict__ ohi,
                                                   unsigned short* __restrict__ olo,
                                                   int n) {
    constexpr int FB = D / 4;
    constexpr int G  = 64 / FB;
    constexpr int U  = 8;
    constexpr int UG = U * G;
    int wid  = (blockIdx.x * 256 + threadIdx.x) >> 6;
    int lane = threadIdx.x & 63;
    int fb = lane & (FB - 1);
    int g  = lane / FB;
    int waveCount = gridDim.x * 4;
    const float4* h4 = (const float4*)h;

    for (int node = wid; node < n; node += waveCount) {
        int beg = rowptr[node], end = rowptr[node + 1];
        float4 a0 = {0, 0, 0, 0}, a1 = {0, 0, 0, 0}, a2 = {0, 0, 0, 0}, a3 = {0, 0, 0, 0};

        for (int base = beg; base < end; base += 64) {
            int m = end - base; if (m > 64) m = 64;
            int cv = colidx[base + (lane < m ? lane : 0)];
            int nb = (m + UG - 1) / UG;       // wave-uniform trip count
            for (int b = 0; b < nb; b++) {
                int s[U]; float w[U];
#pragma unroll
                for (int u = 0; u < U; u++) {
                    int j = b * UG + u * G + g;
                    int q = j < m ? j : 0;
                    w[u] = j < m ? 1.f : 0.f;
                    s[u] = __shfl(cv, q);
                }
                float4 v[U];
#pragma unroll
                for (int u = 0; u < U; u++)
                    v[u] = h4[(size_t)s[u] * FB + fb];
#pragma unroll
                for (int u = 0; u < U; u += 4) {
                    a0.x = fmaf(v[u].x, w[u], a0.x); a0.y = fmaf(v[u].y, w[u], a0.y);
                    a0.z = fmaf(v[u].z, w[u], a0.z); a0.w = fmaf(v[u].w, w[u], a0.w);
                    a1.x = fmaf(v[u+1].x, w[u+1], a1.x); a1.y = fmaf(v[u+1].y, w[u+1], a1.y);
                    a1.z = fmaf(v[u+1].z, w[u+1], a1.z); a1.w = fmaf(v[u+1].w, w[u+1], a1.w);
                    a2.x = fmaf(v[u+2].x, w[u+2], a2.x); a2.y = fmaf(v[u+2].y, w[u+2], a2.y);
                    a2.z = fmaf(v[u+2].z, w[u+2], a2.z); a2.w = fmaf(v[u+2].w, w[u+2], a2.w);
                    a3.x = fmaf(v[u+3].x, w[u+3], a3.x); a3.y = fmaf(v[u+3].y, w[u+3], a3.y);
                    a3.z = fmaf(v[u+3].z, w[u+3], a3.z); a3.w = fmaf(v[u+3].w, w[u+3], a3.w);
                }
            }
        }

        float4 acc;
        acc.x = (a0.x + a1.x) + (a2.x + a3.x);
        acc.y = (a0.y + a1.y) + (a2.y + a3.y);
        acc.z = (a0.z + a1.z) + (a2.z + a3.z);
        acc.w = (a0.w + a1.w) + (a2.w + a3.w);
#pragma unroll
        for (int off = FB; off < 64; off <<= 1) {
            acc.x += __shfl_xor(acc.x, off);
            acc.y += __shfl_xor(acc.y, off);
            acc.z += __shfl_xor(acc.z, off);
            acc.w += __shfl_xor(acc.w, off);
        }
        if (g == 0) {
            float nd = ndst[node];
            float4 bv = ((const float4*)bias)[fb];
            float4 v;
            v.x = acc.x * nd + bv.x;
            v.y = acc.y * nd + bv.y;
            v.z = acc.z * nd + bv.z;
            v.w = acc.w * nd + bv.w;
            if (MODE == 1) {
                v.x = tanhf(v.x); v.y = tanhf(v.y);
                v.z = tanhf(v.z); v.w = tanhf(v.w);
                ushort4 hv, lv;
                hv.x = f2bf_rne(v.x); lv.x = f2bf_rne(v.x - bf2f(hv.x));
                hv.y = f2bf_rne(v.y); lv.y = f2bf_rne(v.y - bf2f(hv.y));
                hv.z = f2bf_rne(v.z); lv.z = f2bf_rne(v.z - bf2f(hv.z));
                hv.w = f2bf_rne(v.w); lv.w = f2bf_rne(v.w - bf2f(hv.w));
                *(ushort4*)&ohi[(size_t)node * D + fb * 4] = hv;
                *(ushort4*)&olo[(size_t)node * D + fb * 4] = lv;
            } else {
                ((float4*)out)[(size_t)node * FB + fb] = v;
            }
        }
    }
}

// ---------------- host ----------------

extern "C" void kernel_launch(void* const* d_in, const int* in_sizes, int n_in,
                              void* d_out, int out_size, void* d_ws, size_t ws_size,
                              hipStream_t stream) {
    const float* features = (const float*)d_in[0];
    const int* edges      = (const int*)d_in[1];
    const float* W0 = (const float*)d_in[2]; const float* b0 = (const float*)d_in[3];
    const float* W1 = (const float*)d_in[4]; const float* b1 = (const float*)d_in[5];
    const float* W2 = (const float*)d_in[6]; const float* b2 = (const float*)d_in[7];
    const float* W3 = (const float*)d_in[8]; const float* b3 = (const float*)d_in[9];
    float* out = (float*)d_out;

    const int N = in_sizes[0] / 128;
    const int E = in_sizes[1] / 2;
    const int* src = edges;
    const int* dst = edges + E;
    const int K = (N + 63) >> 6;
    const int chunk = (E + CB - 1) / CB;
    const int scanN = K * CB;
    const int n2 = 2 * scanN;
    const int numTiles = (n2 + SCAN_TILE - 1) / SCAN_TILE;
    const size_t dynLds = (size_t)2 * K * sizeof(int);

    char* p = (char*)d_ws;
    float* bufH            = (float*)p;          p += (size_t)N * 128 * 4;
    unsigned short* xhi    = (unsigned short*)p; p += (size_t)N * 128 * 2;
    unsigned short* xlo    = (unsigned short*)p; p += (size_t)N * 128 * 2;
    int*   rowptr = (int*)p;   p += (((size_t)(N + 1) * 4 + 15) / 16) * 16;
    int*   colidx = (int*)p;   p += (size_t)E * 4;
    float* nsrc   = (float*)p; p += (size_t)N * 4;
    float* ndst   = (float*)p; p += (size_t)N * 4;
    int*   tilesum= (int*)p;   p += (((size_t)(numTiles + 1) * 4 + 15) / 16) * 16;
    unsigned short* wt0h = (unsigned short*)p; p += 16384 * 2;
    unsigned short* wt0l = (unsigned short*)p; p += 16384 * 2;
    unsigned short* wt1h = (unsigned short*)p; p += 16384 * 2;
    unsigned short* wt1l = (unsigned short*)p; p += 16384 * 2;
    unsigned short* wt2h = (unsigned short*)p; p += 16384 * 2;
    unsigned short* wt2l = (unsigned short*)p; p += 16384 * 2;
    unsigned short* wt3h = (unsigned short*)p; p += 8192 * 2;
    unsigned short* wt3l = (unsigned short*)p; p += 8192 * 2;

    // transient counting-sort buffers aliased into xhi/xlo region
    char* q = (char*)xhi;
    int* sortedAll = (int*)q; q += (size_t)2 * E * 4;
    int* gH        = (int*)q; q += (size_t)n2 * 4;
    int* gHS       = (int*)q; q += (size_t)(n2 + 1) * 4;

    k_prepW_all<<<224, 256, 0, stream>>>(W0, W1, W2, W3, wt0h, wt0l, wt1h, wt1l,
                                         wt2h, wt2l, wt3h, wt3l);
    k_bucket_hist<<<CB, 256, dynLds, stream>>>(src, dst, gH, E, K, scanN, chunk);
    k_scan_partial<<<numTiles, 256, 0, stream>>>(gH, tilesum, n2);
    k_scan_tiles<<<1, 64, 0, stream>>>(tilesum, gHS, numTiles, n2);
    k_scan_final<<<numTiles, 256, 0, stream>>>(gH, tilesum, gHS, n2);
    k_bucket_scatter<<<CB, 256, dynLds, stream>>>(src, dst, gHS, sortedAll, E, K, scanN, chunk);
    k_fine<<<2 * K, 256, 0, stream>>>(sortedAll, gHS, rowptr, colidx, nsrc, ndst, E, K, scanN, N);

    int gblk = (N + 63) / 64;
    int ablk = 8192;
    k_gemm_hyb<128, 0><<<gblk, 256, 0, stream>>>(features, nullptr, nullptr, wt0h, wt0l, nsrc, bufH, N);
    k_aggregate<128, 1><<<ablk, 256, 0, stream>>>(bufH, rowptr, colidx, ndst, b0, nullptr, xhi, xlo, N);
    k_gemm_hyb<128, 1><<<gblk, 256, 0, stream>>>(nullptr, xhi, xlo, wt1h, wt1l, nsrc, bufH, N);
    k_aggregate<128, 1><<<ablk, 256, 0, stream>>>(bufH, rowptr, colidx, ndst, b1, nullptr, xhi, xlo, N);
    k_gemm_hyb<128, 1><<<gblk, 256, 0, stream>>>(nullptr, xhi, xlo, wt2h, wt2l, nsrc, bufH, N);
    k_aggregate<128, 1><<<ablk, 256, 0, stream>>>(bufH, rowptr, colidx, ndst, b2, nullptr, xhi, xlo, N);
    k_gemm_hyb<64, 1><<<gblk, 256, 0, stream>>>(nullptr, xhi, xlo, wt3h, wt3l, nsrc, bufH, N);
    k_aggregate<64, 0><<<ablk, 256, 0, stream>>>(bufH, rowptr, colidx, ndst, b3, out, nullptr, nullptr, N);
}